// Round 25
// baseline (152.253 us; speedup 1.0000x reference)
//
#include <hip/hip_runtime.h>
#include <hip/hip_bf16.h>

#define N_PTS 50000
#define NNB   32
#define KP    15
#define DIN   64
#define DOUT  1024
#define KDIM  (KP*DIN)    // 960
#define NB    16
#define SIGMA_INV (1.0f/0.3f)

#define BM 64
#define BN 64
#define BK 64
#define NKT (KDIM/BK)               // 15
#define RB_FULL 784                 // worst-case row blocks, %8==0
#define NCB (DOUT/BN)               // 16
#define NWG (RB_FULL*NCB)           // 12544 logical tiles
#define PGRID 2048                  // persistent blocks (8/CU), %8==0
#define NSEG 196                    // 256-point segments
#define WT_BLOCKS 240               // 15 x 16 tiles of 64x64
#define PSB 4                       // psum batch span (measured <=2, margin 4)

typedef __attribute__((ext_vector_type(8))) short bf16x8;
typedef __attribute__((ext_vector_type(4))) float f32x4;

#define GLD16(gsrc, ldst) \
  __builtin_amdgcn_global_load_lds((const __attribute__((address_space(1))) char*)(gsrc), \
                                   (__attribute__((address_space(3))) char*)(ldst), 16, 0, 0)

// ---------------- Kernel 1: fused Wt-transpose + KPConv ---------------------
__global__ __launch_bounds__(256) void prep_kernel(
    const float* __restrict__ W, __hip_bfloat16* __restrict__ Wt,
    const float* __restrict__ pos, const float* __restrict__ feats,
    const float* __restrict__ kpts, const int* __restrict__ nidx,
    __hip_bfloat16* __restrict__ g, int* __restrict__ flag,
    int* __restrict__ bcnt) {
  __shared__ union {
    float t[64][65];
    struct { float h[4][16][33]; int cnts; } kc;
  } sm;
  int tid = threadIdx.x;
  if (blockIdx.x < WT_BLOCKS) {
    int i = blockIdx.x;
    int k0 = (i % 15) * 64;
    int o0 = (i / 15) * 64;
    int tx = tid & 63, ty = tid >> 6;
    for (int r = ty; r < 64; r += 4) sm.t[r][tx] = W[(size_t)(k0 + r)*DOUT + o0 + tx];
    __syncthreads();
    for (int r = ty; r < 64; r += 4)
      Wt[(size_t)(o0 + r)*KDIM + k0 + tx] = __float2bfloat16(sm.t[tx][r]);
    return;
  }
  int w = tid >> 6, lane = tid & 63;
  if (tid == 0) sm.kc.cnts = 0;
  __syncthreads();
  int n = (blockIdx.x - WT_BLOCKS) * 4 + w;
  if (n < N_PTS) {
    int myj = lane & 31;
    int khalf = lane >> 5;
    int id0 = nidx[n*NNB + myj];
    float px = pos[n*3+0], py = pos[n*3+1], pz = pos[n*3+2];
    float rx = pos[id0*3+0] - px;
    float ry = pos[id0*3+1] - py;
    float rz = pos[id0*3+2] - pz;
    bool anyact = false;
    float hreg[8];
    #pragma unroll
    for (int i = 0; i < 8; ++i) {
      int k = 2*i + khalf;
      float h = 0.0f;
      if (k < KP) {
        float dx = rx - kpts[k*3+0];
        float dy = ry - kpts[k*3+1];
        float dz = rz - kpts[k*3+2];
        float d = sqrtf(dx*dx + dy*dy + dz*dz);
        h = 1.0f - d * SIGMA_INV;
        h = h > 0.0f ? h : 0.0f;
        anyact |= (h > 0.0f);
      }
      hreg[i] = h;
    }
    unsigned long long bal = __ballot(anyact);
    if (bal) {                                  // wave-uniform
      unsigned int actj = (unsigned int)(bal | (bal >> 32));
      if ((actj >> myj) & 1) {
        #pragma unroll
        for (int i = 0; i < 8; ++i) {
          int k = 2*i + khalf;
          if (k < KP) sm.kc.h[w][k][myj] = hreg[i];
        }
      }
      float acc[KP];
      #pragma unroll
      for (int k = 0; k < KP; ++k) acc[k] = 0.0f;
      while (actj) {
        int j = __ffs(actj) - 1;
        actj &= actj - 1;
        int id = __shfl(id0, j);
        float f = feats[(size_t)id*DIN + lane];
        #pragma unroll
        for (int k = 0; k < KP; ++k) acc[k] += sm.kc.h[w][k][j] * f;
      }
      size_t base = (size_t)n*KDIM;
      #pragma unroll
      for (int k = 0; k < KP; ++k)
        g[base + k*DIN + lane] = __float2bfloat16(acc[k]);
    }
    if (lane == 0) {
      int active = (bal != 0ull) ? 1 : 0;
      flag[n] = active;
      if (active) atomicAdd(&sm.kc.cnts, 1);
    }
  }
  __syncthreads();
  if (tid == 0 && sm.kc.cnts) atomicAdd(&bcnt[(blockIdx.x - WT_BLOCKS) >> 6], sm.kc.cnts);
}

// ---------------- Kernel C0: fill rowlist + bidc (self-scanning) ------------
__global__ __launch_bounds__(256) void fill_kernel(
    const int* __restrict__ flag, const int* __restrict__ bcnt,
    const int* __restrict__ batch, int* __restrict__ rowlist,
    int* __restrict__ bidc, int* __restrict__ mact) {
  __shared__ int s[256];
  __shared__ int boff_l;
  int tid = threadIdx.x;
  int bc = (tid < NSEG) ? bcnt[tid] : 0;
  s[tid] = (tid < (int)blockIdx.x) ? bc : 0;
  __syncthreads();
  for (int d = 1; d < 256; d <<= 1) {
    int v = (tid >= d) ? s[tid-d] : 0;
    __syncthreads();
    s[tid] += v;
    __syncthreads();
  }
  if (tid == 255) boff_l = s[255];
  __syncthreads();
  int boff = boff_l;
  int n = blockIdx.x*256 + tid;
  int f = (n < N_PTS) ? flag[n] : 0;
  s[tid] = f;
  __syncthreads();
  for (int d = 1; d < 256; d <<= 1) {
    int v = (tid >= d) ? s[tid-d] : 0;
    __syncthreads();
    s[tid] += v;
    __syncthreads();
  }
  if (f) {
    int sl = boff + s[tid] - 1;
    rowlist[sl] = n;
    bidc[sl] = batch[n];
  }
  if (blockIdx.x == NSEG-1 && tid == 255) *mact = boff + s[255];
}

// ---------------- Kernel 2: persistent-CTA MFMA GEMM ------------------------
// 2048 physical blocks wg-stride over 12544 logical tiles. 2048%8==0 keeps
// wg&7 (XCD) and cb=t&15 constant per block; rb strides by 128. Inactive
// logical tiles are a uniform 2-inst skip (no dispatch). Per-iteration
// barrier seals previous epilogue before psum/bid reuse.
__global__ __launch_bounds__(256, 8) void gemm_mfma_pool(
    const __hip_bfloat16* __restrict__ g, const __hip_bfloat16* __restrict__ Wt,
    const int* __restrict__ rowlist, const int* __restrict__ bidc,
    const int* __restrict__ mact, float* __restrict__ partial) {
  __shared__ __align__(16) char lA[BM*128];  // 8KB
  __shared__ __align__(16) char lB[BN*128];  // 8KB
  __shared__ float psum[PSB][BN];            // 1KB
  __shared__ int bid[BM];
  int Ma = *mact;
  int tid = threadIdx.x;
  int lane = tid & 63, w = tid >> 6;
  int wr = w >> 1, wc = w & 1;
  int gc = (tid & 7) ^ ((tid >> 3) & 7);

  for (int wg = blockIdx.x; wg < NWG; wg += PGRID) {
    int xg = wg & 7, t = wg >> 3;
    int rb = ((t >> 4) << 3) + xg;            // bijective onto [0,784)
    int cb = t & 15;
    int r0 = rb*BM, c0 = cb*BN;
    if (r0 >= Ma) continue;                   // uniform skip

    __syncthreads();                          // seal previous iteration's epilogue

    const __hip_bfloat16* pA[2];
    #pragma unroll
    for (int i = 0; i < 2; ++i) {
      int slot = r0 + i*32 + (tid >> 3);
      int rl = (slot < Ma) ? rowlist[slot] : 0;
      pA[i] = g + (size_t)rl*KDIM + gc*8;
    }
    const __hip_bfloat16* pB[2];
    #pragma unroll
    for (int i = 0; i < 2; ++i)
      pB[i] = Wt + (size_t)(c0 + i*32 + (tid >> 3))*KDIM + gc*8;

    if (tid < BM) bid[tid] = (r0 + tid < Ma) ? bidc[r0 + tid] : -1;
    for (int z = tid; z < PSB*BN; z += 256) (&psum[0][0])[z] = 0.0f;

    f32x4 acc[2][2] = {};

    for (int kt = 0; kt < NKT; ++kt) {
      int k0 = kt*BK;
      #pragma unroll
      for (int i = 0; i < 2; ++i) GLD16(pA[i] + k0, lA + (i*256 + tid)*16);
      #pragma unroll
      for (int i = 0; i < 2; ++i) GLD16(pB[i] + k0, lB + (i*256 + tid)*16);
      __syncthreads();
      #pragma unroll
      for (int ks = 0; ks < 2; ++ks) {
        bf16x8 af[2], bfr[2];
        #pragma unroll
        for (int m = 0; m < 2; ++m) {
          int row = wr*32 + m*16 + (lane & 15);
          int ch = (ks*4 + (lane >> 4)) ^ (row & 7);
          af[m] = *(const bf16x8*)(lA + row*128 + ch*16);
        }
        #pragma unroll
        for (int n = 0; n < 2; ++n) {
          int row = wc*32 + n*16 + (lane & 15);
          int ch = (ks*4 + (lane >> 4)) ^ (row & 7);
          bfr[n] = *(const bf16x8*)(lB + row*128 + ch*16);
        }
        #pragma unroll
        for (int m = 0; m < 2; ++m)
          #pragma unroll
          for (int n = 0; n < 2; ++n)
            acc[m][n] = __builtin_amdgcn_mfma_f32_16x16x32_bf16(af[m], bfr[n], acc[m][n], 0, 0, 0);
      }
      __syncthreads();
    }

    int bmin = bid[0];
    int q = lane >> 4;
    #pragma unroll 1
    for (int phase = 0; phase < 8; ++phase) {
      if (wr*4 + q == phase) {
        #pragma unroll
        for (int n = 0; n < 2; ++n) {
          int c = wc*32 + n*16 + (lane & 15);
          float run = 0.0f; int curb = -2;
          #pragma unroll
          for (int m = 0; m < 2; ++m) {
            #pragma unroll
            for (int j = 0; j < 4; ++j) {
              int r = wr*32 + m*16 + q*4 + j;
              int b = bid[r];
              float v = acc[m][n][j];
              v = v > 0.0f ? v : 0.1f*v;
              if (b != curb) {
                if (curb >= 0) { int bo = curb - bmin; if (bo < PSB) psum[bo][c] += run; }
                run = 0.0f; curb = b;
              }
              run += v;
            }
          }
          if (curb >= 0) { int bo = curb - bmin; if (bo < PSB) psum[bo][c] += run; }
        }
      }
      __syncthreads();
    }
    // trimmed write: only batches present in this rb (bidc monotone)
    int lastv = (r0 + BM <= Ma) ? (BM-1) : (Ma - 1 - r0);
    int bmax = bid[lastv];
    int nbw = bmax - bmin + 1;
    if (nbw > PSB) nbw = PSB;
    for (int z = tid; z < nbw*BN; z += 256) {
      int bo = z >> 6, c = z & 63;
      partial[((size_t)rb*NB + bmin + bo)*DOUT + c0 + c] = psum[bo][c];
    }
  }
}

// ---------------- Kernel 3: reduce+mean+MLP L1 — rb-range per batch ---------
__global__ __launch_bounds__(512) void mlpA_kernel(
    const float* __restrict__ partial, const int* __restrict__ batch,
    const int* __restrict__ bidc, const int* __restrict__ mact,
    const float* __restrict__ w1, float* __restrict__ part1) {
  __shared__ float red[16][128];
  __shared__ float pl[128];
  __shared__ float h1p[4][512];
  int s = blockIdx.x, b = blockIdx.y, t = threadIdx.x;
  int Ma = *mact;
  int clb, cub;
  { int l = 0, r = Ma; while (l < r) { int m = (l+r)>>1; if (bidc[m] <  b) l = m+1; else r = m; } clb = l; }
  { int l = 0, r = Ma; while (l < r) { int m = (l+r)>>1; if (bidc[m] <= b) l = m+1; else r = m; } cub = l; }
  int rb0 = clb >> 6;
  int rb1 = (cub > clb) ? ((cub - 1) >> 6) : (rb0 - 1);
  {
    int seg = t >> 5, q = t & 31;
    float4 v = {0.f, 0.f, 0.f, 0.f};
    for (int rb = rb0 + seg; rb <= rb1; rb += 16) {
      const float4 p = *(const float4*)&partial[((size_t)rb*NB + b)*DOUT + s*128 + q*4];
      v.x += p.x; v.y += p.y; v.z += p.z; v.w += p.w;
    }
    *(float4*)&red[seg][q*4] = v;
  }
  __syncthreads();
  if (t < 128) {
    float sum = 0.0f;
    #pragma unroll
    for (int e = 0; e < 16; ++e) sum += red[e][t];
    int lb, ub;
    { int l = 0, r = N_PTS; while (l < r) { int m = (l+r)>>1; if (batch[m] <  b) l = m+1; else r = m; } lb = l; }
    { int l = 0, r = N_PTS; while (l < r) { int m = (l+r)>>1; if (batch[m] <= b) l = m+1; else r = m; } ub = l; }
    pl[t] = sum / fmaxf((float)(ub - lb), 1.0f);
  }
  __syncthreads();
  {
    int oq = t & 127, kseg = t >> 7;
    float4 a = {0.f, 0.f, 0.f, 0.f};
    #pragma unroll 8
    for (int i = 0; i < 32; ++i) {
      int k = kseg*32 + i;
      float p = pl[k];
      const float4 wv = *(const float4*)&w1[(size_t)(s*128 + k)*512 + oq*4];
      a.x += p*wv.x; a.y += p*wv.y; a.z += p*wv.z; a.w += p*wv.w;
    }
    *(float4*)&h1p[kseg][oq*4] = a;
  }
  __syncthreads();
  float r1 = (h1p[0][t] + h1p[1][t]) + (h1p[2][t] + h1p[3][t]);
  part1[((size_t)b*8 + s)*512 + t] = r1;
}

// ---------------- Kernel 4: MLP L2+L3 — 512 thr, float4 loads ---------------
__global__ __launch_bounds__(512) void mlpBC_kernel(
    const float* __restrict__ part1, const float* __restrict__ b1,
    const float* __restrict__ w2, const float* __restrict__ b2,
    const float* __restrict__ w3, const float* __restrict__ b3,
    float* __restrict__ out) {
  __shared__ float hs[512];
  __shared__ float h2p[8][256];
  __shared__ float h2l[256];
  __shared__ float o3p[8][152];
  int b = blockIdx.x, t = threadIdx.x;
  {
    float v = b1[t];
    #pragma unroll
    for (int s = 0; s < 8; ++s) v += part1[((size_t)b*8 + s)*512 + t];
    hs[t] = fmaxf(v, 0.0f);
  }
  __syncthreads();
  {
    int oq = t & 63, kseg = t >> 6;
    float4 a = {0.f, 0.f, 0.f, 0.f};
    #pragma unroll 8
    for (int i = 0; i < 64; ++i) {
      int j = kseg*64 + i;
      float p = hs[j];
      const float4 wv = *(const float4*)&w2[(size_t)j*256 + oq*4];
      a.x += p*wv.x; a.y += p*wv.y; a.z += p*wv.z; a.w += p*wv.w;
    }
    *(float4*)&h2p[kseg][oq*4] = a;
  }
  __syncthreads();
  if (t < 256) {
    float v = b2[t];
    #pragma unroll
    for (int e = 0; e < 8; ++e) v += h2p[e][t];
    h2l[t] = fmaxf(v, 0.0f);
  }
  __syncthreads();
  if (t < 304) {
    int oq = t % 38, kseg = t / 38;
    float4 a = {0.f, 0.f, 0.f, 0.f};
    #pragma unroll 8
    for (int i = 0; i < 32; ++i) {
      int j = kseg*32 + i;
      float p = h2l[j];
      const float4 wv = *(const float4*)&w3[(size_t)j*152 + oq*4];
      a.x += p*wv.x; a.y += p*wv.y; a.z += p*wv.z; a.w += p*wv.w;
    }
    *(float4*)&o3p[kseg][oq*4] = a;
  }
  __syncthreads();
  if (t < 152) {
    float v = b3[t];
    #pragma unroll
    for (int e = 0; e < 8; ++e) v += o3p[e][t];
    out[b*152 + t] = v;
  }
}

// ---------------- launch -----------------------------------------------------
extern "C" void kernel_launch(void* const* d_in, const int* in_sizes, int n_in,
                              void* d_out, int out_size, void* d_ws, size_t ws_size,
                              hipStream_t stream) {
  (void)in_sizes; (void)n_in; (void)out_size; (void)ws_size;
  const float* pos   = (const float*)d_in[0];
  const float* feats = (const float*)d_in[1];
  const float* kpts  = (const float*)d_in[2];
  const float* kpw   = (const float*)d_in[3];
  const float* w1    = (const float*)d_in[4];
  const float* b1    = (const float*)d_in[5];
  const float* w2    = (const float*)d_in[6];
  const float* b2    = (const float*)d_in[7];
  const float* w3    = (const float*)d_in[8];
  const float* b3    = (const float*)d_in[9];
  const int* nidx    = (const int*)d_in[10];
  const int* batch   = (const int*)d_in[11];
  float* out = (float*)d_out;

  char* ws = (char*)d_ws;
  const size_t off_g        = 0;                         // 50000*960*2 = 96,000,000
  const size_t off_bidc     = 96000000;                  // 200,704
  const size_t off_rowlist  = off_bidc + 200704;
  const size_t off_flag     = off_rowlist + 200704;
  const size_t off_bcnt     = off_flag + 200704;         // 1024
  const size_t off_mact     = off_bcnt + 1024;           // 64
  const size_t off_wt       = off_mact + 64;             // 1,966,080
  const size_t off_partial  = off_wt + 1966080;          // 51,380,224
  const size_t off_p1       = off_partial + 51380224;    // 262,144
  __hip_bfloat16* g  = (__hip_bfloat16*)(ws + off_g);
  int* bidc    = (int*)(ws + off_bidc);
  int* rowlist = (int*)(ws + off_rowlist);
  int* flag    = (int*)(ws + off_flag);
  int* bcnt    = (int*)(ws + off_bcnt);
  int* mact    = (int*)(ws + off_mact);
  __hip_bfloat16* wt = (__hip_bfloat16*)(ws + off_wt);
  float* partial = (float*)(ws + off_partial);
  float* part1   = (float*)(ws + off_p1);

  hipMemsetAsync(bcnt, 0, 1024, stream);
  prep_kernel<<<WT_BLOCKS + (N_PTS+3)/4, 256, 0, stream>>>(
      kpw, wt, pos, feats, kpts, nidx, g, flag, bcnt);
  fill_kernel<<<NSEG, 256, 0, stream>>>(flag, bcnt, batch, rowlist, bidc, mact);
  gemm_mfma_pool<<<PGRID, 256, 0, stream>>>(g, wt, rowlist, bidc, mact, partial);
  mlpA_kernel<<<dim3(8, NB), 512, 0, stream>>>(partial, batch, bidc, mact, w1, part1);
  mlpBC_kernel<<<NB, 512, 0, stream>>>(part1, b1, w2, b2, w3, b3, out);
}

// Round 26
// 149.924 us; speedup vs baseline: 1.0155x; 1.0155x over previous
//
#include <hip/hip_runtime.h>
#include <hip/hip_bf16.h>

#define N_PTS 50000
#define NNB   32
#define KP    15
#define DIN   64
#define DOUT  1024
#define KDIM  (KP*DIN)    // 960
#define NB    16
#define SIGMA_INV (1.0f/0.3f)

#define BM 64
#define BN 64
#define BK 64
#define NKT (KDIM/BK)               // 15
#define RB_FULL 784                 // worst-case row blocks, %8==0
#define NCB (DOUT/BN)               // 16
#define NWG (RB_FULL*NCB)           // 12544
#define NSEG 196                    // 256-point segments
#define WT_BLOCKS 240               // 15 x 16 tiles of 64x64
#define PSB 4                       // psum batch span (measured <=2, margin 4)

typedef __attribute__((ext_vector_type(8))) short bf16x8;
typedef __attribute__((ext_vector_type(4))) float f32x4;

#define GLD16(gsrc, ldst) \
  __builtin_amdgcn_global_load_lds((const __attribute__((address_space(1))) char*)(gsrc), \
                                   (__attribute__((address_space(3))) char*)(ldst), 16, 0, 0)

// ---------------- Kernel 1: fused Wt-transpose + KPConv ---------------------
__global__ __launch_bounds__(256) void prep_kernel(
    const float* __restrict__ W, __hip_bfloat16* __restrict__ Wt,
    const float* __restrict__ pos, const float* __restrict__ feats,
    const float* __restrict__ kpts, const int* __restrict__ nidx,
    __hip_bfloat16* __restrict__ g, int* __restrict__ flag,
    int* __restrict__ bcnt) {
  __shared__ union {
    float t[64][65];
    struct { float h[4][16][33]; int cnts; } kc;
  } sm;
  int tid = threadIdx.x;
  if (blockIdx.x < WT_BLOCKS) {
    int i = blockIdx.x;
    int k0 = (i % 15) * 64;
    int o0 = (i / 15) * 64;
    int tx = tid & 63, ty = tid >> 6;
    for (int r = ty; r < 64; r += 4) sm.t[r][tx] = W[(size_t)(k0 + r)*DOUT + o0 + tx];
    __syncthreads();
    for (int r = ty; r < 64; r += 4)
      Wt[(size_t)(o0 + r)*KDIM + k0 + tx] = __float2bfloat16(sm.t[tx][r]);
    return;
  }
  int w = tid >> 6, lane = tid & 63;
  if (tid == 0) sm.kc.cnts = 0;
  __syncthreads();
  int n = (blockIdx.x - WT_BLOCKS) * 4 + w;
  if (n < N_PTS) {
    int myj = lane & 31;
    int khalf = lane >> 5;
    int id0 = nidx[n*NNB + myj];
    float px = pos[n*3+0], py = pos[n*3+1], pz = pos[n*3+2];
    float rx = pos[id0*3+0] - px;
    float ry = pos[id0*3+1] - py;
    float rz = pos[id0*3+2] - pz;
    bool anyact = false;
    float hreg[8];
    #pragma unroll
    for (int i = 0; i < 8; ++i) {
      int k = 2*i + khalf;
      float h = 0.0f;
      if (k < KP) {
        float dx = rx - kpts[k*3+0];
        float dy = ry - kpts[k*3+1];
        float dz = rz - kpts[k*3+2];
        float d = sqrtf(dx*dx + dy*dy + dz*dz);
        h = 1.0f - d * SIGMA_INV;
        h = h > 0.0f ? h : 0.0f;
        anyact |= (h > 0.0f);
      }
      hreg[i] = h;
    }
    unsigned long long bal = __ballot(anyact);
    if (bal) {                                  // wave-uniform
      unsigned int actj = (unsigned int)(bal | (bal >> 32));
      if ((actj >> myj) & 1) {
        #pragma unroll
        for (int i = 0; i < 8; ++i) {
          int k = 2*i + khalf;
          if (k < KP) sm.kc.h[w][k][myj] = hreg[i];
        }
      }
      float acc[KP];
      #pragma unroll
      for (int k = 0; k < KP; ++k) acc[k] = 0.0f;
      while (actj) {
        int j = __ffs(actj) - 1;
        actj &= actj - 1;
        int id = __shfl(id0, j);
        float f = feats[(size_t)id*DIN + lane];
        #pragma unroll
        for (int k = 0; k < KP; ++k) acc[k] += sm.kc.h[w][k][j] * f;
      }
      size_t base = (size_t)n*KDIM;
      #pragma unroll
      for (int k = 0; k < KP; ++k)
        g[base + k*DIN + lane] = __float2bfloat16(acc[k]);
    }
    if (lane == 0) {
      int active = (bal != 0ull) ? 1 : 0;
      flag[n] = active;
      if (active) atomicAdd(&sm.kc.cnts, 1);
    }
  }
  __syncthreads();
  if (tid == 0 && sm.kc.cnts) atomicAdd(&bcnt[(blockIdx.x - WT_BLOCKS) >> 6], sm.kc.cnts);
}

// ---------------- Kernel C0: fill rowlist + bidc (self-scanning) ------------
__global__ __launch_bounds__(256) void fill_kernel(
    const int* __restrict__ flag, const int* __restrict__ bcnt,
    const int* __restrict__ batch, int* __restrict__ rowlist,
    int* __restrict__ bidc, int* __restrict__ mact) {
  __shared__ int s[256];
  __shared__ int boff_l;
  int tid = threadIdx.x;
  int bc = (tid < NSEG) ? bcnt[tid] : 0;
  s[tid] = (tid < (int)blockIdx.x) ? bc : 0;
  __syncthreads();
  for (int d = 1; d < 256; d <<= 1) {
    int v = (tid >= d) ? s[tid-d] : 0;
    __syncthreads();
    s[tid] += v;
    __syncthreads();
  }
  if (tid == 255) boff_l = s[255];
  __syncthreads();
  int boff = boff_l;
  int n = blockIdx.x*256 + tid;
  int f = (n < N_PTS) ? flag[n] : 0;
  s[tid] = f;
  __syncthreads();
  for (int d = 1; d < 256; d <<= 1) {
    int v = (tid >= d) ? s[tid-d] : 0;
    __syncthreads();
    s[tid] += v;
    __syncthreads();
  }
  if (f) {
    int sl = boff + s[tid] - 1;
    rowlist[sl] = n;
    bidc[sl] = batch[n];
  }
  if (blockIdx.x == NSEG-1 && tid == 255) *mact = boff + s[255];
}

// ---------------- Kernel 2: MFMA GEMM — psum [4][64], 8 blocks/CU -----------
__global__ __launch_bounds__(256, 8) void gemm_mfma_pool(
    const __hip_bfloat16* __restrict__ g, const __hip_bfloat16* __restrict__ Wt,
    const int* __restrict__ rowlist, const int* __restrict__ bidc,
    const int* __restrict__ mact, float* __restrict__ partial) {
  __shared__ __align__(16) char lA[BM*128];  // 8KB
  __shared__ __align__(16) char lB[BN*128];  // 8KB
  __shared__ float psum[PSB][BN];            // 1KB
  __shared__ int bid[BM];
  int wg = blockIdx.x;
  int xg = wg & 7, t = wg >> 3;
  int rb = ((t >> 4) << 3) + xg;              // bijective onto [0,784)
  int cb = t & 15;
  int Ma = *mact;
  int r0 = rb*BM, c0 = cb*BN;
  int tid = threadIdx.x;
  if (r0 >= Ma) return;
  int lane = tid & 63, w = tid >> 6;
  int wr = w >> 1, wc = w & 1;

  int gc = (tid & 7) ^ ((tid >> 3) & 7);
  const __hip_bfloat16* pA[2];
  #pragma unroll
  for (int i = 0; i < 2; ++i) {
    int slot = r0 + i*32 + (tid >> 3);
    int rl = (slot < Ma) ? rowlist[slot] : 0;
    pA[i] = g + (size_t)rl*KDIM + gc*8;
  }
  const __hip_bfloat16* pB[2];
  #pragma unroll
  for (int i = 0; i < 2; ++i)
    pB[i] = Wt + (size_t)(c0 + i*32 + (tid >> 3))*KDIM + gc*8;

  if (tid < BM) bid[tid] = (r0 + tid < Ma) ? bidc[r0 + tid] : -1;
  for (int z = tid; z < PSB*BN; z += 256) (&psum[0][0])[z] = 0.0f;

  f32x4 acc[2][2] = {};

  for (int kt = 0; kt < NKT; ++kt) {
    int k0 = kt*BK;
    #pragma unroll
    for (int i = 0; i < 2; ++i) GLD16(pA[i] + k0, lA + (i*256 + tid)*16);
    #pragma unroll
    for (int i = 0; i < 2; ++i) GLD16(pB[i] + k0, lB + (i*256 + tid)*16);
    __syncthreads();
    #pragma unroll
    for (int ks = 0; ks < 2; ++ks) {
      bf16x8 af[2], bfr[2];
      #pragma unroll
      for (int m = 0; m < 2; ++m) {
        int row = wr*32 + m*16 + (lane & 15);
        int ch = (ks*4 + (lane >> 4)) ^ (row & 7);
        af[m] = *(const bf16x8*)(lA + row*128 + ch*16);
      }
      #pragma unroll
      for (int n = 0; n < 2; ++n) {
        int row = wc*32 + n*16 + (lane & 15);
        int ch = (ks*4 + (lane >> 4)) ^ (row & 7);
        bfr[n] = *(const bf16x8*)(lB + row*128 + ch*16);
      }
      #pragma unroll
      for (int m = 0; m < 2; ++m)
        #pragma unroll
        for (int n = 0; n < 2; ++n)
          acc[m][n] = __builtin_amdgcn_mfma_f32_16x16x32_bf16(af[m], bfr[n], acc[m][n], 0, 0, 0);
    }
    __syncthreads();
  }

  int bmin = bid[0];
  int q = lane >> 4;
  #pragma unroll 1
  for (int phase = 0; phase < 8; ++phase) {
    if (wr*4 + q == phase) {
      #pragma unroll
      for (int n = 0; n < 2; ++n) {
        int c = wc*32 + n*16 + (lane & 15);
        float run = 0.0f; int curb = -2;
        #pragma unroll
        for (int m = 0; m < 2; ++m) {
          #pragma unroll
          for (int j = 0; j < 4; ++j) {
            int r = wr*32 + m*16 + q*4 + j;
            int b = bid[r];
            float v = acc[m][n][j];
            v = v > 0.0f ? v : 0.1f*v;
            if (b != curb) {
              if (curb >= 0) { int bo = curb - bmin; if (bo < PSB) psum[bo][c] += run; }
              run = 0.0f; curb = b;
            }
            run += v;
          }
        }
        if (curb >= 0) { int bo = curb - bmin; if (bo < PSB) psum[bo][c] += run; }
      }
    }
    __syncthreads();
  }
  // trimmed write: only batches present in this rb (bidc monotone)
  int lastv = (r0 + BM <= Ma) ? (BM-1) : (Ma - 1 - r0);
  int bmax = bid[lastv];
  int nbw = bmax - bmin + 1;
  if (nbw > PSB) nbw = PSB;
  for (int z = tid; z < nbw*BN; z += 256) {
    int bo = z >> 6, c = z & 63;
    partial[((size_t)rb*NB + bmin + bo)*DOUT + c0 + c] = psum[bo][c];
  }
}

// ---------------- Kernel 3: reduce+mean+MLP L1 — rb-range per batch ---------
__global__ __launch_bounds__(512) void mlpA_kernel(
    const float* __restrict__ partial, const int* __restrict__ batch,
    const int* __restrict__ bidc, const int* __restrict__ mact,
    const float* __restrict__ w1, float* __restrict__ part1) {
  __shared__ float red[16][128];
  __shared__ float pl[128];
  __shared__ float h1p[4][512];
  int s = blockIdx.x, b = blockIdx.y, t = threadIdx.x;
  int Ma = *mact;
  int clb, cub;
  { int l = 0, r = Ma; while (l < r) { int m = (l+r)>>1; if (bidc[m] <  b) l = m+1; else r = m; } clb = l; }
  { int l = 0, r = Ma; while (l < r) { int m = (l+r)>>1; if (bidc[m] <= b) l = m+1; else r = m; } cub = l; }
  int rb0 = clb >> 6;
  int rb1 = (cub > clb) ? ((cub - 1) >> 6) : (rb0 - 1);
  {
    int seg = t >> 5, q = t & 31;
    float4 v = {0.f, 0.f, 0.f, 0.f};
    for (int rb = rb0 + seg; rb <= rb1; rb += 16) {
      const float4 p = *(const float4*)&partial[((size_t)rb*NB + b)*DOUT + s*128 + q*4];
      v.x += p.x; v.y += p.y; v.z += p.z; v.w += p.w;
    }
    *(float4*)&red[seg][q*4] = v;
  }
  __syncthreads();
  if (t < 128) {
    float sum = 0.0f;
    #pragma unroll
    for (int e = 0; e < 16; ++e) sum += red[e][t];
    int lb, ub;
    { int l = 0, r = N_PTS; while (l < r) { int m = (l+r)>>1; if (batch[m] <  b) l = m+1; else r = m; } lb = l; }
    { int l = 0, r = N_PTS; while (l < r) { int m = (l+r)>>1; if (batch[m] <= b) l = m+1; else r = m; } ub = l; }
    pl[t] = sum / fmaxf((float)(ub - lb), 1.0f);
  }
  __syncthreads();
  {
    int oq = t & 127, kseg = t >> 7;
    float4 a = {0.f, 0.f, 0.f, 0.f};
    #pragma unroll 8
    for (int i = 0; i < 32; ++i) {
      int k = kseg*32 + i;
      float p = pl[k];
      const float4 wv = *(const float4*)&w1[(size_t)(s*128 + k)*512 + oq*4];
      a.x += p*wv.x; a.y += p*wv.y; a.z += p*wv.z; a.w += p*wv.w;
    }
    *(float4*)&h1p[kseg][oq*4] = a;
  }
  __syncthreads();
  float r1 = (h1p[0][t] + h1p[1][t]) + (h1p[2][t] + h1p[3][t]);
  part1[((size_t)b*8 + s)*512 + t] = r1;
}

// ---------------- Kernel 4: MLP L2+L3 — 512 thr, float4 loads ---------------
__global__ __launch_bounds__(512) void mlpBC_kernel(
    const float* __restrict__ part1, const float* __restrict__ b1,
    const float* __restrict__ w2, const float* __restrict__ b2,
    const float* __restrict__ w3, const float* __restrict__ b3,
    float* __restrict__ out) {
  __shared__ float hs[512];
  __shared__ float h2p[8][256];
  __shared__ float h2l[256];
  __shared__ float o3p[8][152];
  int b = blockIdx.x, t = threadIdx.x;
  {
    float v = b1[t];
    #pragma unroll
    for (int s = 0; s < 8; ++s) v += part1[((size_t)b*8 + s)*512 + t];
    hs[t] = fmaxf(v, 0.0f);
  }
  __syncthreads();
  {
    int oq = t & 63, kseg = t >> 6;
    float4 a = {0.f, 0.f, 0.f, 0.f};
    #pragma unroll 8
    for (int i = 0; i < 64; ++i) {
      int j = kseg*64 + i;
      float p = hs[j];
      const float4 wv = *(const float4*)&w2[(size_t)j*256 + oq*4];
      a.x += p*wv.x; a.y += p*wv.y; a.z += p*wv.z; a.w += p*wv.w;
    }
    *(float4*)&h2p[kseg][oq*4] = a;
  }
  __syncthreads();
  if (t < 256) {
    float v = b2[t];
    #pragma unroll
    for (int e = 0; e < 8; ++e) v += h2p[e][t];
    h2l[t] = fmaxf(v, 0.0f);
  }
  __syncthreads();
  if (t < 304) {
    int oq = t % 38, kseg = t / 38;
    float4 a = {0.f, 0.f, 0.f, 0.f};
    #pragma unroll 8
    for (int i = 0; i < 32; ++i) {
      int j = kseg*32 + i;
      float p = h2l[j];
      const float4 wv = *(const float4*)&w3[(size_t)j*152 + oq*4];
      a.x += p*wv.x; a.y += p*wv.y; a.z += p*wv.z; a.w += p*wv.w;
    }
    *(float4*)&o3p[kseg][oq*4] = a;
  }
  __syncthreads();
  if (t < 152) {
    float v = b3[t];
    #pragma unroll
    for (int e = 0; e < 8; ++e) v += o3p[e][t];
    out[b*152 + t] = v;
  }
}

// ---------------- launch -----------------------------------------------------
extern "C" void kernel_launch(void* const* d_in, const int* in_sizes, int n_in,
                              void* d_out, int out_size, void* d_ws, size_t ws_size,
                              hipStream_t stream) {
  (void)in_sizes; (void)n_in; (void)out_size; (void)ws_size;
  const float* pos   = (const float*)d_in[0];
  const float* feats = (const float*)d_in[1];
  const float* kpts  = (const float*)d_in[2];
  const float* kpw   = (const float*)d_in[3];
  const float* w1    = (const float*)d_in[4];
  const float* b1    = (const float*)d_in[5];
  const float* w2    = (const float*)d_in[6];
  const float* b2    = (const float*)d_in[7];
  const float* w3    = (const float*)d_in[8];
  const float* b3    = (const float*)d_in[9];
  const int* nidx    = (const int*)d_in[10];
  const int* batch   = (const int*)d_in[11];
  float* out = (float*)d_out;

  char* ws = (char*)d_ws;
  const size_t off_g        = 0;                         // 50000*960*2 = 96,000,000
  const size_t off_bidc     = 96000000;                  // 200,704
  const size_t off_rowlist  = off_bidc + 200704;
  const size_t off_flag     = off_rowlist + 200704;
  const size_t off_bcnt     = off_flag + 200704;         // 1024
  const size_t off_mact     = off_bcnt + 1024;           // 64
  const size_t off_wt       = off_mact + 64;             // 1,966,080
  const size_t off_partial  = off_wt + 1966080;          // 51,380,224
  const size_t off_p1       = off_partial + 51380224;    // 262,144
  __hip_bfloat16* g  = (__hip_bfloat16*)(ws + off_g);
  int* bidc    = (int*)(ws + off_bidc);
  int* rowlist = (int*)(ws + off_rowlist);
  int* flag    = (int*)(ws + off_flag);
  int* bcnt    = (int*)(ws + off_bcnt);
  int* mact    = (int*)(ws + off_mact);
  __hip_bfloat16* wt = (__hip_bfloat16*)(ws + off_wt);
  float* partial = (float*)(ws + off_partial);
  float* part1   = (float*)(ws + off_p1);

  hipMemsetAsync(bcnt, 0, 1024, stream);
  prep_kernel<<<WT_BLOCKS + (N_PTS+3)/4, 256, 0, stream>>>(
      kpw, wt, pos, feats, kpts, nidx, g, flag, bcnt);
  fill_kernel<<<NSEG, 256, 0, stream>>>(flag, bcnt, batch, rowlist, bidc, mact);
  gemm_mfma_pool<<<NWG, 256, 0, stream>>>(g, wt, rowlist, bidc, mact, partial);
  mlpA_kernel<<<dim3(8, NB), 512, 0, stream>>>(partial, batch, bidc, mact, w1, part1);
  mlpBC_kernel<<<NB, 512, 0, stream>>>(part1, b1, w2, b2, w3, b3, out);
}